// Round 11
// baseline (184.912 us; speedup 1.0000x reference)
//
#include <hip/hip_runtime.h>
#include <math.h>

#define Hdim 1024
#define VOC 32000
#define LSEQ 128
#define BSZ 64

typedef __attribute__((ext_vector_type(8))) short bf16x8;
typedef __attribute__((ext_vector_type(4))) float f32x4;

__device__ __forceinline__ float fast_tanhf(float x) {
    return 1.0f - 2.0f / (__expf(2.0f * x) + 1.0f);
}
__device__ __forceinline__ float sigmoidf(float x) {
    return 1.0f / (1.0f + __expf(-x));
}
__device__ __forceinline__ short f2bf(float f) {
    unsigned u = __float_as_uint(f);
    unsigned r = (u + 0x7fffu + ((u >> 16) & 1u)) >> 16;
    return (short)r;
}

// async global->LDS, 16 bytes per lane (dest linear: base + lane*16)
__device__ __forceinline__ void gl_lds16(const short* g, short* l) {
    __builtin_amdgcn_global_load_lds(
        (const __attribute__((address_space(1))) unsigned*)g,
        (__attribute__((address_space(3))) unsigned*)l, 16, 0, 0);
}

// 16 consecutive f32 -> 16 bf16 at dst (2x 16B stores)
__device__ __forceinline__ void stage16(const float* __restrict__ src, short* dst) {
    f32x4 v0 = *(const f32x4*)(src);
    f32x4 v1 = *(const f32x4*)(src + 4);
    f32x4 v2 = *(const f32x4*)(src + 8);
    f32x4 v3 = *(const f32x4*)(src + 12);
    bf16x8 p0, p1;
    p0[0] = f2bf(v0[0]); p0[1] = f2bf(v0[1]); p0[2] = f2bf(v0[2]); p0[3] = f2bf(v0[3]);
    p0[4] = f2bf(v1[0]); p0[5] = f2bf(v1[1]); p0[6] = f2bf(v1[2]); p0[7] = f2bf(v1[3]);
    p1[0] = f2bf(v2[0]); p1[1] = f2bf(v2[1]); p1[2] = f2bf(v2[2]); p1[3] = f2bf(v2[3]);
    p1[4] = f2bf(v3[0]); p1[5] = f2bf(v3[1]); p1[6] = f2bf(v3[2]); p1[7] = f2bf(v3[3]);
    *(bf16x8*)(dst) = p0;
    *(bf16x8*)(dst + 8) = p1;
}

// ---------------------------------------------------------------------------
// Kernel 1: conversions + embedding gather (blocks 0..1023, grid-stride)
//           ∥ u-GEMM partials from f32 inputs (blocks 1024..1055).
// ---------------------------------------------------------------------------
__global__ __launch_bounds__(256) void conv_ug(
    const float* __restrict__ enc, const float* __restrict__ attnW,
    const float* __restrict__ hidden, const float* __restrict__ emb,
    const int* __restrict__ ids,
    short* __restrict__ enc_bf, short* __restrict__ attnW1_bf,
    short* __restrict__ hidden_bf, short* __restrict__ x_bf,
    float* __restrict__ u4)
{
    __shared__ short As[64 * 72];
    __shared__ short Bs[128 * 72];

    if (blockIdx.x < 1024) {
        const int NG_ENC = 1048576, NG_AW = 131072, NG_H = 8192, NG_EMB = 8192;
        const int total = NG_ENC + NG_AW + NG_H + NG_EMB;
        for (int g = blockIdx.x * 256 + threadIdx.x; g < total; g += 1024 * 256) {
            const float* src; short* dst;
            if (g < NG_ENC) {
                src = enc + (size_t)g * 8; dst = enc_bf + (size_t)g * 8;
            } else if (g < NG_ENC + NG_AW) {
                const int i = g - NG_ENC, h = i >> 7, c = i & 127;
                src = attnW + (size_t)h * 2048 + c * 8;       // W1 cols only
                dst = attnW1_bf + (size_t)h * 1024 + c * 8;   // compact ld 1024
            } else if (g < NG_ENC + NG_AW + NG_H) {
                const int i = g - NG_ENC - NG_AW;
                src = hidden + (size_t)i * 8; dst = hidden_bf + (size_t)i * 8;
            } else {
                const int i = g - NG_ENC - NG_AW - NG_H, b = i >> 7, c = i & 127;
                src = emb + (size_t)ids[b] * Hdim + c * 8;
                dst = x_bf + (size_t)b * 2048 + c * 8;        // x[:,0:1024] = emb
            }
            f32x4 a = *(const f32x4*)(src);
            f32x4 b = *(const f32x4*)(src + 4);
            bf16x8 p;
            p[0] = f2bf(a[0]); p[1] = f2bf(a[1]); p[2] = f2bf(a[2]); p[3] = f2bf(a[3]);
            p[4] = f2bf(b[0]); p[5] = f2bf(b[1]); p[6] = f2bf(b[2]); p[7] = f2bf(b[3]);
            *(bf16x8*)(dst) = p;
        }
        return;
    }

    // ---- ugemm from f32: u4[s] = hidden @ W2^T, split-K x4, tile 64x128 ----
    const int id = blockIdx.x - 1024;          // 0..31
    const int n0 = (id & 7) * 128;
    const int kstart = (id >> 3) * 256;
    float* Cp = u4 + (size_t)(id >> 3) * (BSZ * Hdim);

    const int t = threadIdx.x;
    const int lane = t & 63, wave = t >> 6;
    const int lr = lane & 15, kh = lane >> 4;
    const int ar = t >> 2, ac = (t & 3) * 16;
    const int br = t >> 1, bc = (t & 1) * 32;

    f32x4 acc[4][2] = {};

    for (int k0 = 0; k0 < 256; k0 += 64) {
        const int kg = kstart + k0;
        stage16(hidden + (size_t)ar * Hdim + kg + ac, As + ar * 72 + ac);
        stage16(attnW + (size_t)(n0 + br) * 2048 + 1024 + kg + bc,      Bs + br * 72 + bc);
        stage16(attnW + (size_t)(n0 + br) * 2048 + 1024 + kg + bc + 16, Bs + br * 72 + bc + 16);
        __syncthreads();
#pragma unroll
        for (int kk = 0; kk < 64; kk += 32) {
            bf16x8 af[4], bfr[2];
#pragma unroll
            for (int mi = 0; mi < 4; ++mi)
                af[mi] = *(const bf16x8*)(As + (mi * 16 + lr) * 72 + kk + kh * 8);
#pragma unroll
            for (int ni = 0; ni < 2; ++ni)
                bfr[ni] = *(const bf16x8*)(Bs + (wave * 32 + ni * 16 + lr) * 72 + kk + kh * 8);
#pragma unroll
            for (int mi = 0; mi < 4; ++mi)
#pragma unroll
                for (int ni = 0; ni < 2; ++ni)
                    acc[mi][ni] = __builtin_amdgcn_mfma_f32_16x16x32_bf16(
                        af[mi], bfr[ni], acc[mi][ni], 0, 0, 0);
        }
        __syncthreads();
    }

#pragma unroll
    for (int mi = 0; mi < 4; ++mi)
#pragma unroll
        for (int ni = 0; ni < 2; ++ni) {
            const int col = n0 + wave * 32 + ni * 16 + lr;
#pragma unroll
            for (int r = 0; r < 4; ++r)
                Cp[(size_t)(mi * 16 + kh * 4 + r) * Hdim + col] = acc[mi][ni][r];
        }
}

// ---------------------------------------------------------------------------
// Streaming skinny GEMM body (512 thr, 64x64 tile, BK=64), dbuf LDS,
// one barrier per k-tile. smem: 36864 bytes carved by caller.
// ---------------------------------------------------------------------------
__device__ __forceinline__ void sgemm_body(
    char* smem,
    const short* __restrict__ A, int lda,
    const float* __restrict__ B, int ldb,
    const float* __restrict__ bias,
    float* __restrict__ C, int ldc,
    int n0, int kstart, int klen, bool rmw)
{
    short* As = (short*)smem;               // [2][64*72]
    short* Bs = (short*)(smem + 18432);     // [2][64*72]

    const int t = threadIdx.x;
    const int lane = t & 63, wave = t >> 6;
    const int wm = wave >> 2, wn = wave & 3;
    const int lr = lane & 15, kh = lane >> 4;

    const int sr = t >> 3, sc = (t & 7) * 8;
    const short* Ap = A + (size_t)sr * lda + kstart + sc;
    const float* Bp = B + (size_t)(n0 + sr) * ldb + kstart + sc;

    const int nkt = klen >> 6;

    bf16x8 pa = *(const bf16x8*)(Ap);
    f32x4 pb0 = *(const f32x4*)(Bp);
    f32x4 pb1 = *(const f32x4*)(Bp + 4);
    *(bf16x8*)(&As[sr * 72 + sc]) = pa;
    {
        bf16x8 q;
        q[0] = f2bf(pb0[0]); q[1] = f2bf(pb0[1]); q[2] = f2bf(pb0[2]); q[3] = f2bf(pb0[3]);
        q[4] = f2bf(pb1[0]); q[5] = f2bf(pb1[1]); q[6] = f2bf(pb1[2]); q[7] = f2bf(pb1[3]);
        *(bf16x8*)(&Bs[sr * 72 + sc]) = q;
    }

    f32x4 acc[2] = {};

    for (int kt = 0; kt < nkt; ++kt) {
        const int co = (kt & 1) * 4608;
        if (kt + 1 < nkt) {
            const int kn = (kt + 1) * 64;
            pa  = *(const bf16x8*)(Ap + kn);
            pb0 = *(const f32x4*)(Bp + kn);
            pb1 = *(const f32x4*)(Bp + kn + 4);
        }
        __syncthreads();
#pragma unroll
        for (int kk = 0; kk < 64; kk += 32) {
            bf16x8 af0 = *(const bf16x8*)(&As[co + (wm * 32 + lr) * 72 + kk + kh * 8]);
            bf16x8 af1 = *(const bf16x8*)(&As[co + (wm * 32 + 16 + lr) * 72 + kk + kh * 8]);
            bf16x8 bfr = *(const bf16x8*)(&Bs[co + (wn * 16 + lr) * 72 + kk + kh * 8]);
            acc[0] = __builtin_amdgcn_mfma_f32_16x16x32_bf16(af0, bfr, acc[0], 0, 0, 0);
            acc[1] = __builtin_amdgcn_mfma_f32_16x16x32_bf16(af1, bfr, acc[1], 0, 0, 0);
        }
        if (kt + 1 < nkt) {
            const int no = ((kt + 1) & 1) * 4608;
            *(bf16x8*)(&As[no + sr * 72 + sc]) = pa;
            bf16x8 q;
            q[0] = f2bf(pb0[0]); q[1] = f2bf(pb0[1]); q[2] = f2bf(pb0[2]); q[3] = f2bf(pb0[3]);
            q[4] = f2bf(pb1[0]); q[5] = f2bf(pb1[1]); q[6] = f2bf(pb1[2]); q[7] = f2bf(pb1[3]);
            *(bf16x8*)(&Bs[no + sr * 72 + sc]) = q;
        }
    }

    const int col = n0 + wn * 16 + lr;
    const float bb = bias ? bias[col] : 0.0f;
#pragma unroll
    for (int mi = 0; mi < 2; ++mi)
#pragma unroll
        for (int r = 0; r < 4; ++r) {
            const size_t idx = (size_t)(wm * 32 + mi * 16 + kh * 4 + r) * ldc + col;
            const float prev = rmw ? C[idx] : 0.0f;
            C[idx] = prev + acc[mi][r] + bb;
        }
}

// ---------------------------------------------------------------------------
// Attention-scores body (128x128 tile, 8 waves, gload_lds staging).
// smem: 32KB tiles + 2KB red; u-table overlays tiles after the K-loop.
// ---------------------------------------------------------------------------
__device__ __forceinline__ void attn_body(
    char* smem,
    const short* __restrict__ enc_bf, const short* __restrict__ W1_bf, // ld 1024
    const float* __restrict__ u4, const float* __restrict__ attnb,
    const float* __restrict__ vvec, float* __restrict__ scores_part,
    int aid)
{
    short* As = (short*)smem;                 // [128*64]
    short* Bs = (short*)(smem + 16384);       // [128*64]
    float* red = (float*)(smem + 32768);      // [8][64]

    const int t = threadIdx.x;
    const int lane = t & 63, wave = t >> 6;
    const int wr = wave >> 2, wc = wave & 3;
    const int lr = lane & 15, kh = lane >> 4;
    const int m0 = (aid & 63) * 128;
    const int n0 = (aid >> 6) * 128;

    const int o1 = t * 16;
    const int o2 = 8192 + t * 16;
    const int r1 = o1 >> 7, c1 = (o1 & 127) >> 1;
    const int r2 = o2 >> 7, c2 = (o2 & 127) >> 1;

    f32x4 acc[4][2] = {};

    for (int kg = 0; kg < Hdim; kg += 64) {
        gl_lds16(enc_bf + (size_t)(m0 + r1) * Hdim + kg + c1, As + (o1 >> 1));
        gl_lds16(enc_bf + (size_t)(m0 + r2) * Hdim + kg + c2, As + (o2 >> 1));
        gl_lds16(W1_bf + (size_t)(n0 + r1) * Hdim + kg + c1, Bs + (o1 >> 1));
        gl_lds16(W1_bf + (size_t)(n0 + r2) * Hdim + kg + c2, Bs + (o2 >> 1));
        __syncthreads();
#pragma unroll
        for (int kk = 0; kk < 64; kk += 32) {
            bf16x8 af[4], bfr[2];
#pragma unroll
            for (int mi = 0; mi < 4; ++mi)
                af[mi] = *(const bf16x8*)(As + (wr * 64 + mi * 16 + lr) * 64 + kk + kh * 8);
#pragma unroll
            for (int ni = 0; ni < 2; ++ni)
                bfr[ni] = *(const bf16x8*)(Bs + (wc * 32 + ni * 16 + lr) * 64 + kk + kh * 8);
#pragma unroll
            for (int mi = 0; mi < 4; ++mi)
#pragma unroll
                for (int ni = 0; ni < 2; ++ni)
                    acc[mi][ni] = __builtin_amdgcn_mfma_f32_16x16x32_bf16(
                        af[mi], bfr[ni], acc[mi][ni], 0, 0, 0);
        }
        __syncthreads();
    }

    float* u_lds = (float*)smem;              // overlay (tiles dead)
    for (int i = t; i < 64 * 128; i += 512) {
        const int b = i >> 7, hl = i & 127;
        const size_t g = (size_t)b * Hdim + n0 + hl;
        u_lds[i] = u4[g] + u4[65536 + g] + u4[2 * 65536 + g] + u4[3 * 65536 + g]
                 + attnb[n0 + hl];
    }
    __syncthreads();

    float sv[16];
#pragma unroll
    for (int mi = 0; mi < 4; ++mi)
#pragma unroll
        for (int r = 0; r < 4; ++r) {
            const int b = mi * 16 + kh * 4 + r;     // m0 % 64 == 0
            float s = 0.0f;
#pragma unroll
            for (int ni = 0; ni < 2; ++ni) {
                const int hl = wc * 32 + ni * 16 + lr;
                const float e = fast_tanhf(acc[mi][ni][r] + u_lds[b * 128 + hl]);
                s += e * vvec[n0 + hl];
            }
            sv[mi * 4 + r] = s;
        }
#pragma unroll
    for (int i = 0; i < 16; ++i) {
#pragma unroll
        for (int d = 1; d < 16; d <<= 1)
            sv[i] += __shfl_xor(sv[i], d, 64);
    }
    if (lr == 0) {
#pragma unroll
        for (int mi = 0; mi < 4; ++mi)
#pragma unroll
            for (int r = 0; r < 4; ++r)
                red[wave * 64 + mi * 16 + kh * 4 + r] = sv[mi * 4 + r];
    }
    __syncthreads();
    if (t < 128) {
        const int wrr = t >> 6, lrow = t & 63;
        scores_part[(size_t)(aid >> 6) * (LSEQ * BSZ) + m0 + t] =
            red[(wrr * 4 + 0) * 64 + lrow] + red[(wrr * 4 + 1) * 64 + lrow] +
            red[(wrr * 4 + 2) * 64 + lrow] + red[(wrr * 4 + 3) * 64 + lrow];
    }
}

// ---------------------------------------------------------------------------
// Kernel 2: fused attn (512 blocks) ∥ outproj emb-part (500 blocks), 1:1 mix.
// __launch_bounds__(512, 6): cap VGPR (~85) so 3 blocks/CU co-reside —
// this is what R9's standalone attn had; without it the fused kernel's
// register allocation collapses occupancy to 1 block/CU (R10 regression).
// ---------------------------------------------------------------------------
__global__ __launch_bounds__(512, 6) void attn_oproj(
    const short* __restrict__ enc_bf, const short* __restrict__ W1_bf,
    const float* __restrict__ u4, const float* __restrict__ attnb,
    const float* __restrict__ vvec, float* __restrict__ scores_part,
    const short* __restrict__ x_bf, const float* __restrict__ out_W,
    const float* __restrict__ out_b, float* __restrict__ logits)
{
    __shared__ __align__(16) char smem[36864];
    const int i = blockIdx.x;
    if (i < 1000) {
        if ((i & 1) == 0)
            attn_body(smem, enc_bf, W1_bf, u4, attnb, vvec, scores_part, i >> 1);
        else
            sgemm_body(smem, x_bf, 2048, out_W + 2048, 3072, out_b,
                       logits, VOC, (i >> 1) * 64, 0, 1024, false);
    } else {
        attn_body(smem, enc_bf, W1_bf, u4, attnb, vvec, scores_part,
                  500 + (i - 1000));
    }
}

// ---------------------------------------------------------------------------
// Kernel 3: softmax + weighted context. grid(64 b, 4 hg), 128 thr.
// ---------------------------------------------------------------------------
__global__ __launch_bounds__(128) void softmax_weighted(
    const float* __restrict__ sp,       // [8][8192]
    const short* __restrict__ enc_bf,   // [8192, 1024]
    float* __restrict__ attn_out,       // [B, L]
    short* __restrict__ x_bf,           // [64, 2048] (cols 1024:2048)
    short* __restrict__ hw_bf)          // [64, 2048] (cols 1024:2048)
{
    const int b = blockIdx.x, hg = blockIdx.y, t = threadIdx.x;
    __shared__ float aw[LSEQ];
    __shared__ float red[LSEQ];

    float s = 0.0f;
#pragma unroll
    for (int g = 0; g < 8; ++g) s += sp[g * (LSEQ * BSZ) + t * 64 + b];
    red[t] = s;
    __syncthreads();
    for (int off = 64; off > 0; off >>= 1) {
        if (t < off) red[t] = fmaxf(red[t], red[t + off]);
        __syncthreads();
    }
    const float mx = red[0];
    __syncthreads();
    const float e = __expf(s - mx);
    red[t] = e;
    __syncthreads();
    for (int off = 64; off > 0; off >>= 1) {
        if (t < off) red[t] += red[t + off];
        __syncthreads();
    }
    const float p = e / red[0];
    aw[t] = p;
    if (hg == 0) attn_out[(size_t)b * LSEQ + t] = p;
    __syncthreads();

    const int h = hg * 256 + t * 2;
    float a0 = 0.0f, a1 = 0.0f;
#pragma unroll 8
    for (int l = 0; l < LSEQ; ++l) {
        const unsigned w = *(const unsigned*)(enc_bf + ((size_t)l * BSZ + b) * Hdim + h);
        const float pw = aw[l];
        a0 = fmaf(pw, __uint_as_float(w << 16), a0);
        a1 = fmaf(pw, __uint_as_float(w & 0xffff0000u), a1);
    }
    const unsigned packed = (unsigned)(unsigned short)f2bf(a0)
                          | ((unsigned)(unsigned short)f2bf(a1) << 16);
    *(unsigned*)(x_bf + (size_t)b * 2048 + 1024 + h) = packed;
    *(unsigned*)(hw_bf + (size_t)b * 2048 + 1024 + h) = packed;
}

// ---------------------------------------------------------------------------
// Kernel 4: merged GRU gate GEMMs, split-K x4. grid(96, 4), 512 thr.
// ---------------------------------------------------------------------------
__global__ __launch_bounds__(512) void gxgh_stream(
    const short* __restrict__ x_bf, const float* __restrict__ w_ih,
    const short* __restrict__ hidden_bf, const float* __restrict__ w_hh,
    float* __restrict__ gx4, float* __restrict__ gh4)
{
    __shared__ __align__(16) char smem[36864];
    const size_t P = (size_t)BSZ * 3 * Hdim;
    if (blockIdx.x < 48)
        sgemm_body(smem, x_bf, 2 * Hdim, w_ih, 2 * Hdim, nullptr,
                   gx4 + blockIdx.y * P, 3 * Hdim,
                   blockIdx.x * 64, blockIdx.y * 512, 512, false);
    else
        sgemm_body(smem, hidden_bf, Hdim, w_hh, Hdim, nullptr,
                   gh4 + blockIdx.y * P, 3 * Hdim,
                   (blockIdx.x - 48) * 64, blockIdx.y * 256, 256, false);
}

// ---------------------------------------------------------------------------
// Kernel 5: GRU elementwise; writes h_new (f32 out) + hw_bf[:,0:1024] (bf16).
// ---------------------------------------------------------------------------
__global__ __launch_bounds__(256) void gru_kernel(
    const float* __restrict__ gx4, const float* __restrict__ gh4,
    const float* __restrict__ b_ih, const float* __restrict__ b_hh,
    const float* __restrict__ h0,
    float* __restrict__ hnew_out, short* __restrict__ hw_bf)
{
    const int idx = blockIdx.x * 256 + threadIdx.x;
    const int b = idx >> 10, h = idx & 1023;
    const size_t g3 = (size_t)b * (3 * Hdim);
    const size_t P = (size_t)BSZ * 3 * Hdim;
    float xr = b_ih[h], xz = b_ih[Hdim + h], xn = b_ih[2 * Hdim + h];
    float hr = b_hh[h], hz = b_hh[Hdim + h], hn = b_hh[2 * Hdim + h];
#pragma unroll
    for (int s = 0; s < 4; ++s) {
        xr += gx4[s * P + g3 + h];
        xz += gx4[s * P + g3 + Hdim + h];
        xn += gx4[s * P + g3 + 2 * Hdim + h];
        hr += gh4[s * P + g3 + h];
        hz += gh4[s * P + g3 + Hdim + h];
        hn += gh4[s * P + g3 + 2 * Hdim + h];
    }
    const float r = sigmoidf(xr + hr);
    const float z = sigmoidf(xz + hz);
    const float n = fast_tanhf(xn + r * hn);
    const float hv = (1.0f - z) * n + z * h0[(size_t)b * Hdim + h];
    hnew_out[(size_t)b * Hdim + h] = hv;
    hw_bf[(size_t)b * 2048 + h] = f2bf(hv);
}

// ---------------------------------------------------------------------------
// Kernel 6: logits += [hnew, weighted] @ out_W[:, 0:2048]^T. grid(500), 512.
// ---------------------------------------------------------------------------
__global__ __launch_bounds__(512) void oproj_hw(
    const short* __restrict__ hw_bf, const float* __restrict__ out_W,
    float* __restrict__ logits)
{
    __shared__ __align__(16) char smem[36864];
    sgemm_body(smem, hw_bf, 2048, out_W, 3072, nullptr,
               logits, VOC, blockIdx.x * 64, 0, 2048, true);
}

// ---------------------------------------------------------------------------
extern "C" void kernel_launch(void* const* d_in, const int* in_sizes, int n_in,
                              void* d_out, int out_size, void* d_ws, size_t ws_size,
                              hipStream_t stream)
{
    const int*   ids    = (const int*)d_in[0];
    const float* hidden = (const float*)d_in[1];
    const float* enc    = (const float*)d_in[2];
    const float* emb    = (const float*)d_in[3];
    const float* attnW  = (const float*)d_in[4];
    const float* attnb  = (const float*)d_in[5];
    const float* vvec   = (const float*)d_in[6];
    const float* w_ih   = (const float*)d_in[7];
    const float* w_hh   = (const float*)d_in[8];
    const float* b_ih   = (const float*)d_in[9];
    const float* b_hh   = (const float*)d_in[10];
    const float* out_W  = (const float*)d_in[11];
    const float* out_b  = (const float*)d_in[12];

    float* out        = (float*)d_out;
    float* out_logits = out;
    float* out_hnew   = out + (size_t)BSZ * VOC;
    float* out_attn   = out_hnew + (size_t)BSZ * Hdim;

    float* ws = (float*)d_ws;
    short* enc_bf    = (short*)ws;                  // 4,194,304 f
    short* attnW1_bf = (short*)(ws + 4194304);      // 524,288 f
    short* hidden_bf = (short*)(ws + 4718592);      // 32,768 f
    float* ws_u4     = ws + 4751360;                // 262,144 f
    float* ws_sp     = ws_u4 + 262144;              // 65,536 f
    short* x_bf      = (short*)(ws_sp + 65536);     // 65,536 f
    short* hw_bf     = (short*)(ws_sp + 131072);    // 65,536 f
    float* ws_gx4    = ws_sp + 196608;              // 786,432 f
    float* ws_gh4    = ws_gx4 + 786432;             // 786,432 f

    // 1. conversions + emb gather ∥ u-GEMM partials
    conv_ug<<<dim3(1056), 256, 0, stream>>>(
        enc, attnW, hidden, emb, ids,
        enc_bf, attnW1_bf, hidden_bf, x_bf, ws_u4);

    // 2. fused attn scores ∥ outproj emb-part (1012 blocks)
    attn_oproj<<<dim3(1012), 512, 0, stream>>>(
        enc_bf, attnW1_bf, ws_u4, attnb, vvec, ws_sp,
        x_bf, out_W, out_b, out_logits);

    // 3. softmax + weighted context
    softmax_weighted<<<dim3(BSZ, 4), 128, 0, stream>>>(
        ws_sp, enc_bf, out_attn, x_bf, hw_bf);

    // 4. GRU gate GEMMs
    gxgh_stream<<<dim3(96, 4), 512, 0, stream>>>(
        x_bf, w_ih, hidden_bf, w_hh, ws_gx4, ws_gh4);

    // 5. GRU elementwise
    gru_kernel<<<dim3(BSZ * Hdim / 256), 256, 0, stream>>>(
        ws_gx4, ws_gh4, b_ih, b_hh, hidden, out_hnew, hw_bf);

    // 6. logits += [hnew, weighted] part
    oproj_hw<<<dim3(VOC / 64), 512, 0, stream>>>(
        hw_bf, out_W, out_logits);
}

// Round 12
// 171.228 us; speedup vs baseline: 1.0799x; 1.0799x over previous
//
#include <hip/hip_runtime.h>
#include <math.h>

#define Hdim 1024
#define VOC 32000
#define LSEQ 128
#define BSZ 64

typedef __attribute__((ext_vector_type(8))) short bf16x8;
typedef __attribute__((ext_vector_type(4))) float f32x4;

__device__ __forceinline__ float fast_tanhf(float x) {
    return 1.0f - 2.0f / (__expf(2.0f * x) + 1.0f);
}
__device__ __forceinline__ float sigmoidf(float x) {
    return 1.0f / (1.0f + __expf(-x));
}
__device__ __forceinline__ short f2bf(float f) {
    unsigned u = __float_as_uint(f);
    unsigned r = (u + 0x7fffu + ((u >> 16) & 1u)) >> 16;
    return (short)r;
}

// async global->LDS, 16 bytes per lane (dest linear: base + lane*16)
__device__ __forceinline__ void gl_lds16(const short* g, short* l) {
    __builtin_amdgcn_global_load_lds(
        (const __attribute__((address_space(1))) unsigned*)g,
        (__attribute__((address_space(3))) unsigned*)l, 16, 0, 0);
}

// 16 consecutive f32 -> 16 bf16 at dst (2x 16B stores)
__device__ __forceinline__ void stage16(const float* __restrict__ src, short* dst) {
    f32x4 v0 = *(const f32x4*)(src);
    f32x4 v1 = *(const f32x4*)(src + 4);
    f32x4 v2 = *(const f32x4*)(src + 8);
    f32x4 v3 = *(const f32x4*)(src + 12);
    bf16x8 p0, p1;
    p0[0] = f2bf(v0[0]); p0[1] = f2bf(v0[1]); p0[2] = f2bf(v0[2]); p0[3] = f2bf(v0[3]);
    p0[4] = f2bf(v1[0]); p0[5] = f2bf(v1[1]); p0[6] = f2bf(v1[2]); p0[7] = f2bf(v1[3]);
    p1[0] = f2bf(v2[0]); p1[1] = f2bf(v2[1]); p1[2] = f2bf(v2[2]); p1[3] = f2bf(v2[3]);
    p1[4] = f2bf(v3[0]); p1[5] = f2bf(v3[1]); p1[6] = f2bf(v3[2]); p1[7] = f2bf(v3[3]);
    *(bf16x8*)(dst) = p0;
    *(bf16x8*)(dst + 8) = p1;
}

// ---------------------------------------------------------------------------
// Kernel 1: conversions + embedding gather (blocks 0..1023, grid-stride)
//           ∥ u-GEMM partials from f32 inputs (blocks 1024..1055).
// ---------------------------------------------------------------------------
__global__ __launch_bounds__(256) void conv_ug(
    const float* __restrict__ enc, const float* __restrict__ attnW,
    const float* __restrict__ hidden, const float* __restrict__ emb,
    const int* __restrict__ ids,
    short* __restrict__ enc_bf, short* __restrict__ attnW1_bf,
    short* __restrict__ hidden_bf, short* __restrict__ x_bf,
    float* __restrict__ u4)
{
    __shared__ short As[64 * 72];
    __shared__ short Bs[128 * 72];

    if (blockIdx.x < 1024) {
        const int NG_ENC = 1048576, NG_AW = 131072, NG_H = 8192, NG_EMB = 8192;
        const int total = NG_ENC + NG_AW + NG_H + NG_EMB;
        for (int g = blockIdx.x * 256 + threadIdx.x; g < total; g += 1024 * 256) {
            const float* src; short* dst;
            if (g < NG_ENC) {
                src = enc + (size_t)g * 8; dst = enc_bf + (size_t)g * 8;
            } else if (g < NG_ENC + NG_AW) {
                const int i = g - NG_ENC, h = i >> 7, c = i & 127;
                src = attnW + (size_t)h * 2048 + c * 8;       // W1 cols only
                dst = attnW1_bf + (size_t)h * 1024 + c * 8;   // compact ld 1024
            } else if (g < NG_ENC + NG_AW + NG_H) {
                const int i = g - NG_ENC - NG_AW;
                src = hidden + (size_t)i * 8; dst = hidden_bf + (size_t)i * 8;
            } else {
                const int i = g - NG_ENC - NG_AW - NG_H, b = i >> 7, c = i & 127;
                src = emb + (size_t)ids[b] * Hdim + c * 8;
                dst = x_bf + (size_t)b * 2048 + c * 8;        // x[:,0:1024] = emb
            }
            f32x4 a = *(const f32x4*)(src);
            f32x4 b = *(const f32x4*)(src + 4);
            bf16x8 p;
            p[0] = f2bf(a[0]); p[1] = f2bf(a[1]); p[2] = f2bf(a[2]); p[3] = f2bf(a[3]);
            p[4] = f2bf(b[0]); p[5] = f2bf(b[1]); p[6] = f2bf(b[2]); p[7] = f2bf(b[3]);
            *(bf16x8*)(dst) = p;
        }
        return;
    }

    // ---- ugemm from f32: u4[s] = hidden @ W2^T, split-K x4, tile 64x128 ----
    const int id = blockIdx.x - 1024;          // 0..31
    const int n0 = (id & 7) * 128;
    const int kstart = (id >> 3) * 256;
    float* Cp = u4 + (size_t)(id >> 3) * (BSZ * Hdim);

    const int t = threadIdx.x;
    const int lane = t & 63, wave = t >> 6;
    const int lr = lane & 15, kh = lane >> 4;
    const int ar = t >> 2, ac = (t & 3) * 16;
    const int br = t >> 1, bc = (t & 1) * 32;

    f32x4 acc[4][2] = {};

    for (int k0 = 0; k0 < 256; k0 += 64) {
        const int kg = kstart + k0;
        stage16(hidden + (size_t)ar * Hdim + kg + ac, As + ar * 72 + ac);
        stage16(attnW + (size_t)(n0 + br) * 2048 + 1024 + kg + bc,      Bs + br * 72 + bc);
        stage16(attnW + (size_t)(n0 + br) * 2048 + 1024 + kg + bc + 16, Bs + br * 72 + bc + 16);
        __syncthreads();
#pragma unroll
        for (int kk = 0; kk < 64; kk += 32) {
            bf16x8 af[4], bfr[2];
#pragma unroll
            for (int mi = 0; mi < 4; ++mi)
                af[mi] = *(const bf16x8*)(As + (mi * 16 + lr) * 72 + kk + kh * 8);
#pragma unroll
            for (int ni = 0; ni < 2; ++ni)
                bfr[ni] = *(const bf16x8*)(Bs + (wave * 32 + ni * 16 + lr) * 72 + kk + kh * 8);
#pragma unroll
            for (int mi = 0; mi < 4; ++mi)
#pragma unroll
                for (int ni = 0; ni < 2; ++ni)
                    acc[mi][ni] = __builtin_amdgcn_mfma_f32_16x16x32_bf16(
                        af[mi], bfr[ni], acc[mi][ni], 0, 0, 0);
        }
        __syncthreads();
    }

#pragma unroll
    for (int mi = 0; mi < 4; ++mi)
#pragma unroll
        for (int ni = 0; ni < 2; ++ni) {
            const int col = n0 + wave * 32 + ni * 16 + lr;
#pragma unroll
            for (int r = 0; r < 4; ++r)
                Cp[(size_t)(mi * 16 + kh * 4 + r) * Hdim + col] = acc[mi][ni][r];
        }
}

// ---------------------------------------------------------------------------
// Streaming skinny GEMM body (512 thr, 64x64 tile, BK=64), dbuf LDS,
// one barrier per k-tile. smem: 36864 bytes carved by caller.
// ---------------------------------------------------------------------------
__device__ __forceinline__ void sgemm_body(
    char* smem,
    const short* __restrict__ A, int lda,
    const float* __restrict__ B, int ldb,
    const float* __restrict__ bias,
    float* __restrict__ C, int ldc,
    int n0, int kstart, int klen, bool rmw)
{
    short* As = (short*)smem;               // [2][64*72]
    short* Bs = (short*)(smem + 18432);     // [2][64*72]

    const int t = threadIdx.x;
    const int lane = t & 63, wave = t >> 6;
    const int wm = wave >> 2, wn = wave & 3;
    const int lr = lane & 15, kh = lane >> 4;

    const int sr = t >> 3, sc = (t & 7) * 8;
    const short* Ap = A + (size_t)sr * lda + kstart + sc;
    const float* Bp = B + (size_t)(n0 + sr) * ldb + kstart + sc;

    const int nkt = klen >> 6;

    bf16x8 pa = *(const bf16x8*)(Ap);
    f32x4 pb0 = *(const f32x4*)(Bp);
    f32x4 pb1 = *(const f32x4*)(Bp + 4);
    *(bf16x8*)(&As[sr * 72 + sc]) = pa;
    {
        bf16x8 q;
        q[0] = f2bf(pb0[0]); q[1] = f2bf(pb0[1]); q[2] = f2bf(pb0[2]); q[3] = f2bf(pb0[3]);
        q[4] = f2bf(pb1[0]); q[5] = f2bf(pb1[1]); q[6] = f2bf(pb1[2]); q[7] = f2bf(pb1[3]);
        *(bf16x8*)(&Bs[sr * 72 + sc]) = q;
    }

    f32x4 acc[2] = {};

    for (int kt = 0; kt < nkt; ++kt) {
        const int co = (kt & 1) * 4608;
        if (kt + 1 < nkt) {
            const int kn = (kt + 1) * 64;
            pa  = *(const bf16x8*)(Ap + kn);
            pb0 = *(const f32x4*)(Bp + kn);
            pb1 = *(const f32x4*)(Bp + kn + 4);
        }
        __syncthreads();
#pragma unroll
        for (int kk = 0; kk < 64; kk += 32) {
            bf16x8 af0 = *(const bf16x8*)(&As[co + (wm * 32 + lr) * 72 + kk + kh * 8]);
            bf16x8 af1 = *(const bf16x8*)(&As[co + (wm * 32 + 16 + lr) * 72 + kk + kh * 8]);
            bf16x8 bfr = *(const bf16x8*)(&Bs[co + (wn * 16 + lr) * 72 + kk + kh * 8]);
            acc[0] = __builtin_amdgcn_mfma_f32_16x16x32_bf16(af0, bfr, acc[0], 0, 0, 0);
            acc[1] = __builtin_amdgcn_mfma_f32_16x16x32_bf16(af1, bfr, acc[1], 0, 0, 0);
        }
        if (kt + 1 < nkt) {
            const int no = ((kt + 1) & 1) * 4608;
            *(bf16x8*)(&As[no + sr * 72 + sc]) = pa;
            bf16x8 q;
            q[0] = f2bf(pb0[0]); q[1] = f2bf(pb0[1]); q[2] = f2bf(pb0[2]); q[3] = f2bf(pb0[3]);
            q[4] = f2bf(pb1[0]); q[5] = f2bf(pb1[1]); q[6] = f2bf(pb1[2]); q[7] = f2bf(pb1[3]);
            *(bf16x8*)(&Bs[no + sr * 72 + sc]) = q;
        }
    }

    const int col = n0 + wn * 16 + lr;
    const float bb = bias ? bias[col] : 0.0f;
#pragma unroll
    for (int mi = 0; mi < 2; ++mi)
#pragma unroll
        for (int r = 0; r < 4; ++r) {
            const size_t idx = (size_t)(wm * 32 + mi * 16 + kh * 4 + r) * ldc + col;
            const float prev = rmw ? C[idx] : 0.0f;
            C[idx] = prev + acc[mi][r] + bb;
        }
}

// ---------------------------------------------------------------------------
// Attention-scores body (128x128 tile, 8 waves, gload_lds staging).
// smem: 32KB tiles + 2KB red; u-table overlays tiles after the K-loop.
// ---------------------------------------------------------------------------
__device__ __forceinline__ void attn_body(
    char* smem,
    const short* __restrict__ enc_bf, const short* __restrict__ W1_bf, // ld 1024
    const float* __restrict__ u4, const float* __restrict__ attnb,
    const float* __restrict__ vvec, float* __restrict__ scores_part,
    int aid)
{
    short* As = (short*)smem;                 // [128*64]
    short* Bs = (short*)(smem + 16384);       // [128*64]
    float* red = (float*)(smem + 32768);      // [8][64]

    const int t = threadIdx.x;
    const int lane = t & 63, wave = t >> 6;
    const int wr = wave >> 2, wc = wave & 3;
    const int lr = lane & 15, kh = lane >> 4;
    const int m0 = (aid & 63) * 128;
    const int n0 = (aid >> 6) * 128;

    const int o1 = t * 16;
    const int o2 = 8192 + t * 16;
    const int r1 = o1 >> 7, c1 = (o1 & 127) >> 1;
    const int r2 = o2 >> 7, c2 = (o2 & 127) >> 1;

    f32x4 acc[4][2] = {};

    for (int kg = 0; kg < Hdim; kg += 64) {
        gl_lds16(enc_bf + (size_t)(m0 + r1) * Hdim + kg + c1, As + (o1 >> 1));
        gl_lds16(enc_bf + (size_t)(m0 + r2) * Hdim + kg + c2, As + (o2 >> 1));
        gl_lds16(W1_bf + (size_t)(n0 + r1) * Hdim + kg + c1, Bs + (o1 >> 1));
        gl_lds16(W1_bf + (size_t)(n0 + r2) * Hdim + kg + c2, Bs + (o2 >> 1));
        __syncthreads();
#pragma unroll
        for (int kk = 0; kk < 64; kk += 32) {
            bf16x8 af[4], bfr[2];
#pragma unroll
            for (int mi = 0; mi < 4; ++mi)
                af[mi] = *(const bf16x8*)(As + (wr * 64 + mi * 16 + lr) * 64 + kk + kh * 8);
#pragma unroll
            for (int ni = 0; ni < 2; ++ni)
                bfr[ni] = *(const bf16x8*)(Bs + (wc * 32 + ni * 16 + lr) * 64 + kk + kh * 8);
#pragma unroll
            for (int mi = 0; mi < 4; ++mi)
#pragma unroll
                for (int ni = 0; ni < 2; ++ni)
                    acc[mi][ni] = __builtin_amdgcn_mfma_f32_16x16x32_bf16(
                        af[mi], bfr[ni], acc[mi][ni], 0, 0, 0);
        }
        __syncthreads();
    }

    float* u_lds = (float*)smem;              // overlay (tiles dead)
    for (int i = t; i < 64 * 128; i += 512) {
        const int b = i >> 7, hl = i & 127;
        const size_t g = (size_t)b * Hdim + n0 + hl;
        u_lds[i] = u4[g] + u4[65536 + g] + u4[2 * 65536 + g] + u4[3 * 65536 + g]
                 + attnb[n0 + hl];
    }
    __syncthreads();

    float sv[16];
#pragma unroll
    for (int mi = 0; mi < 4; ++mi)
#pragma unroll
        for (int r = 0; r < 4; ++r) {
            const int b = mi * 16 + kh * 4 + r;     // m0 % 64 == 0
            float s = 0.0f;
#pragma unroll
            for (int ni = 0; ni < 2; ++ni) {
                const int hl = wc * 32 + ni * 16 + lr;
                const float e = fast_tanhf(acc[mi][ni][r] + u_lds[b * 128 + hl]);
                s += e * vvec[n0 + hl];
            }
            sv[mi * 4 + r] = s;
        }
#pragma unroll
    for (int i = 0; i < 16; ++i) {
#pragma unroll
        for (int d = 1; d < 16; d <<= 1)
            sv[i] += __shfl_xor(sv[i], d, 64);
    }
    if (lr == 0) {
#pragma unroll
        for (int mi = 0; mi < 4; ++mi)
#pragma unroll
            for (int r = 0; r < 4; ++r)
                red[wave * 64 + mi * 16 + kh * 4 + r] = sv[mi * 4 + r];
    }
    __syncthreads();
    if (t < 128) {
        const int wrr = t >> 6, lrow = t & 63;
        scores_part[(size_t)(aid >> 6) * (LSEQ * BSZ) + m0 + t] =
            red[(wrr * 4 + 0) * 64 + lrow] + red[(wrr * 4 + 1) * 64 + lrow] +
            red[(wrr * 4 + 2) * 64 + lrow] + red[(wrr * 4 + 3) * 64 + lrow];
    }
}

// ---------------------------------------------------------------------------
// Kernel 2: fused attn (512 blocks) ∥ outproj emb-part (500 blocks).
// Interleave in STRIPES of 8 so both block types spread evenly over the 8
// XCDs (consecutive linear blockIdx round-robins XCDs; R10's even/odd split
// pinned all attn blocks to 4 XCDs — that was the regression).
// Grid = 1016 = 127 stripes (64 attn stripes + 63 sgemm stripes, last 4
// sgemm slots idle).
// ---------------------------------------------------------------------------
__global__ __launch_bounds__(512) void attn_oproj(
    const short* __restrict__ enc_bf, const short* __restrict__ W1_bf,
    const float* __restrict__ u4, const float* __restrict__ attnb,
    const float* __restrict__ vvec, float* __restrict__ scores_part,
    const short* __restrict__ x_bf, const float* __restrict__ out_W,
    const float* __restrict__ out_b, float* __restrict__ logits)
{
    __shared__ __align__(16) char smem[36864];
    const int i = blockIdx.x;
    const int s = i >> 3, r = i & 7;
    if ((s & 1) == 0) {
        const int aid = (s >> 1) * 8 + r;         // 0..511
        attn_body(smem, enc_bf, W1_bf, u4, attnb, vvec, scores_part, aid);
    } else {
        const int gid = (s >> 1) * 8 + r;         // 0..503
        if (gid < 500)
            sgemm_body(smem, x_bf, 2048, out_W + 2048, 3072, out_b,
                       logits, VOC, gid * 64, 0, 1024, false);
    }
}

// ---------------------------------------------------------------------------
// Kernel 3: softmax + weighted context. grid(64 b, 4 hg), 128 thr.
// ---------------------------------------------------------------------------
__global__ __launch_bounds__(128) void softmax_weighted(
    const float* __restrict__ sp,       // [8][8192]
    const short* __restrict__ enc_bf,   // [8192, 1024]
    float* __restrict__ attn_out,       // [B, L]
    short* __restrict__ x_bf,           // [64, 2048] (cols 1024:2048)
    short* __restrict__ hw_bf)          // [64, 2048] (cols 1024:2048)
{
    const int b = blockIdx.x, hg = blockIdx.y, t = threadIdx.x;
    __shared__ float aw[LSEQ];
    __shared__ float red[LSEQ];

    float s = 0.0f;
#pragma unroll
    for (int g = 0; g < 8; ++g) s += sp[g * (LSEQ * BSZ) + t * 64 + b];
    red[t] = s;
    __syncthreads();
    for (int off = 64; off > 0; off >>= 1) {
        if (t < off) red[t] = fmaxf(red[t], red[t + off]);
        __syncthreads();
    }
    const float mx = red[0];
    __syncthreads();
    const float e = __expf(s - mx);
    red[t] = e;
    __syncthreads();
    for (int off = 64; off > 0; off >>= 1) {
        if (t < off) red[t] += red[t + off];
        __syncthreads();
    }
    const float p = e / red[0];
    aw[t] = p;
    if (hg == 0) attn_out[(size_t)b * LSEQ + t] = p;
    __syncthreads();

    const int h = hg * 256 + t * 2;
    float a0 = 0.0f, a1 = 0.0f;
#pragma unroll 8
    for (int l = 0; l < LSEQ; ++l) {
        const unsigned w = *(const unsigned*)(enc_bf + ((size_t)l * BSZ + b) * Hdim + h);
        const float pw = aw[l];
        a0 = fmaf(pw, __uint_as_float(w << 16), a0);
        a1 = fmaf(pw, __uint_as_float(w & 0xffff0000u), a1);
    }
    const unsigned packed = (unsigned)(unsigned short)f2bf(a0)
                          | ((unsigned)(unsigned short)f2bf(a1) << 16);
    *(unsigned*)(x_bf + (size_t)b * 2048 + 1024 + h) = packed;
    *(unsigned*)(hw_bf + (size_t)b * 2048 + 1024 + h) = packed;
}

// ---------------------------------------------------------------------------
// Kernel 4: merged GRU gate GEMMs, split-K x4. grid(96, 4), 512 thr.
// ---------------------------------------------------------------------------
__global__ __launch_bounds__(512) void gxgh_stream(
    const short* __restrict__ x_bf, const float* __restrict__ w_ih,
    const short* __restrict__ hidden_bf, const float* __restrict__ w_hh,
    float* __restrict__ gx4, float* __restrict__ gh4)
{
    __shared__ __align__(16) char smem[36864];
    const size_t P = (size_t)BSZ * 3 * Hdim;
    if (blockIdx.x < 48)
        sgemm_body(smem, x_bf, 2 * Hdim, w_ih, 2 * Hdim, nullptr,
                   gx4 + blockIdx.y * P, 3 * Hdim,
                   blockIdx.x * 64, blockIdx.y * 512, 512, false);
    else
        sgemm_body(smem, hidden_bf, Hdim, w_hh, Hdim, nullptr,
                   gh4 + blockIdx.y * P, 3 * Hdim,
                   (blockIdx.x - 48) * 64, blockIdx.y * 256, 256, false);
}

// ---------------------------------------------------------------------------
// Kernel 5: GRU elementwise; writes h_new (f32 out) + hw_bf[:,0:1024] (bf16).
// ---------------------------------------------------------------------------
__global__ __launch_bounds__(256) void gru_kernel(
    const float* __restrict__ gx4, const float* __restrict__ gh4,
    const float* __restrict__ b_ih, const float* __restrict__ b_hh,
    const float* __restrict__ h0,
    float* __restrict__ hnew_out, short* __restrict__ hw_bf)
{
    const int idx = blockIdx.x * 256 + threadIdx.x;
    const int b = idx >> 10, h = idx & 1023;
    const size_t g3 = (size_t)b * (3 * Hdim);
    const size_t P = (size_t)BSZ * 3 * Hdim;
    float xr = b_ih[h], xz = b_ih[Hdim + h], xn = b_ih[2 * Hdim + h];
    float hr = b_hh[h], hz = b_hh[Hdim + h], hn = b_hh[2 * Hdim + h];
#pragma unroll
    for (int s = 0; s < 4; ++s) {
        xr += gx4[s * P + g3 + h];
        xz += gx4[s * P + g3 + Hdim + h];
        xn += gx4[s * P + g3 + 2 * Hdim + h];
        hr += gh4[s * P + g3 + h];
        hz += gh4[s * P + g3 + Hdim + h];
        hn += gh4[s * P + g3 + 2 * Hdim + h];
    }
    const float r = sigmoidf(xr + hr);
    const float z = sigmoidf(xz + hz);
    const float n = fast_tanhf(xn + r * hn);
    const float hv = (1.0f - z) * n + z * h0[(size_t)b * Hdim + h];
    hnew_out[(size_t)b * Hdim + h] = hv;
    hw_bf[(size_t)b * 2048 + h] = f2bf(hv);
}

// ---------------------------------------------------------------------------
// Kernel 6: logits += [hnew, weighted] @ out_W[:, 0:2048]^T. grid(500), 512.
// ---------------------------------------------------------------------------
__global__ __launch_bounds__(512) void oproj_hw(
    const short* __restrict__ hw_bf, const float* __restrict__ out_W,
    float* __restrict__ logits)
{
    __shared__ __align__(16) char smem[36864];
    sgemm_body(smem, hw_bf, 2048, out_W, 3072, nullptr,
               logits, VOC, blockIdx.x * 64, 0, 2048, true);
}

// ---------------------------------------------------------------------------
extern "C" void kernel_launch(void* const* d_in, const int* in_sizes, int n_in,
                              void* d_out, int out_size, void* d_ws, size_t ws_size,
                              hipStream_t stream)
{
    const int*   ids    = (const int*)d_in[0];
    const float* hidden = (const float*)d_in[1];
    const float* enc    = (const float*)d_in[2];
    const float* emb    = (const float*)d_in[3];
    const float* attnW  = (const float*)d_in[4];
    const float* attnb  = (const float*)d_in[5];
    const float* vvec   = (const float*)d_in[6];
    const float* w_ih   = (const float*)d_in[7];
    const float* w_hh   = (const float*)d_in[8];
    const float* b_ih   = (const float*)d_in[9];
    const float* b_hh   = (const float*)d_in[10];
    const float* out_W  = (const float*)d_in[11];
    const float* out_b  = (const float*)d_in[12];

    float* out        = (float*)d_out;
    float* out_logits = out;
    float* out_hnew   = out + (size_t)BSZ * VOC;
    float* out_attn   = out_hnew + (size_t)BSZ * Hdim;

    float* ws = (float*)d_ws;
    short* enc_bf    = (short*)ws;                  // 4,194,304 f
    short* attnW1_bf = (short*)(ws + 4194304);      // 524,288 f
    short* hidden_bf = (short*)(ws + 4718592);      // 32,768 f
    float* ws_u4     = ws + 4751360;                // 262,144 f
    float* ws_sp     = ws_u4 + 262144;              // 65,536 f
    short* x_bf      = (short*)(ws_sp + 65536);     // 65,536 f
    short* hw_bf     = (short*)(ws_sp + 131072);    // 65,536 f
    float* ws_gx4    = ws_sp + 196608;              // 786,432 f
    float* ws_gh4    = ws_gx4 + 786432;             // 786,432 f

    // 1. conversions + emb gather ∥ u-GEMM partials
    conv_ug<<<dim3(1056), 256, 0, stream>>>(
        enc, attnW, hidden, emb, ids,
        enc_bf, attnW1_bf, hidden_bf, x_bf, ws_u4);

    // 2. fused attn scores ∥ outproj emb-part (1016 blocks, stripe-8 mix)
    attn_oproj<<<dim3(1016), 512, 0, stream>>>(
        enc_bf, attnW1_bf, ws_u4, attnb, vvec, ws_sp,
        x_bf, out_W, out_b, out_logits);

    // 3. softmax + weighted context
    softmax_weighted<<<dim3(BSZ, 4), 128, 0, stream>>>(
        ws_sp, enc_bf, out_attn, x_bf, hw_bf);

    // 4. GRU gate GEMMs
    gxgh_stream<<<dim3(96, 4), 512, 0, stream>>>(
        x_bf, w_ih, hidden_bf, w_hh, ws_gx4, ws_gh4);

    // 5. GRU elementwise
    gru_kernel<<<dim3(BSZ * Hdim / 256), 256, 0, stream>>>(
        ws_gx4, ws_gh4, b_ih, b_hh, hidden, out_hnew, hw_bf);

    // 6. logits += [hnew, weighted] part
    oproj_hw<<<dim3(VOC / 64), 512, 0, stream>>>(
        hw_bf, out_W, out_logits);
}